// Round 18
// baseline (40.770 us; speedup 1.0000x reference)
//
#include <hip/hip_runtime.h>
#include <hip/hip_fp16.h>

#define B_  2048
#define I_  256
#define H_  512
#define D_  768
#define K_  32

typedef unsigned short ushort_t;
typedef unsigned int uint_t;
typedef __attribute__((ext_vector_type(8))) __bf16 bf16x8;
typedef __attribute__((ext_vector_type(4))) float f32x4;
typedef __attribute__((ext_vector_type(2))) _Float16 f16x2;

__device__ __forceinline__ ushort_t f2bf(float f) {
  uint_t u = __float_as_uint(f);
  u += 0x7fffu + ((u >> 16) & 1u);   // RNE
  return (ushort_t)(u >> 16);
}
__device__ __forceinline__ float fast_sigmoid(float x) {
  return 1.f / (1.f + __expf(-x));
}
__device__ __forceinline__ float fast_tanh(float x) {
  float t = __expf(2.f * fabsf(x));          // overflow -> inf -> r = 1
  float r = 1.f - 2.f / (t + 1.f);
  return copysignf(r, x);
}
__device__ __forceinline__ void gload16(const void* g, void* l) {
  __builtin_amdgcn_global_load_lds(
      (const __attribute__((address_space(1))) void*)g,
      (__attribute__((address_space(3))) void*)l, 16, 0, 0);
}
// relu(a*b+c) in ONE inst: VOP3P clamp saturates each f16 lane to [0,1]
__device__ __forceinline__ f16x2 pk_fma_relu(f16x2 a, f16x2 b, f16x2 c) {
  f16x2 r;
  asm("v_pk_fma_f16 %0, %1, %2, %3 clamp" : "=v"(r) : "v"(a), "v"(b), "v"(c));
  return r;
}
// acc += h.lo*w.lo + h.hi*w.hi with fp32 accumulate (v_dot2_f32_f16)
__device__ __forceinline__ float dot2_f32(f16x2 a, f16x2 b, float c) {
  float r;
  asm("v_dot2_f32_f16 %0, %1, %2, %3" : "=v"(r) : "v"(a), "v"(b), "v"(c));
  return r;
}
__device__ __forceinline__ f16x2 pack2f(float a, float b) {
  f16x2 r;
  r[0] = (_Float16)a;
  r[1] = (_Float16)b;
  return r;
}

// ---- K1: bids 0..767 = self-contained MLP (LDS weight transpose + packed-fp16
//      core, 32 b-rows/block, pipelined input loads);
//      bids 768..1151 = Wc -> wcT bf16 (64x64 tiles) ----
__global__ __launch_bounds__(256) void kan_prep(
    const float* __restrict__ x, const float* __restrict__ hp,
    const float* __restrict__ W1, const float* __restrict__ b1,
    const float* __restrict__ W2, const float* __restrict__ b2,
    const float* __restrict__ Wc,
    ushort_t* __restrict__ wcT, ushort_t* __restrict__ uT) {
  __shared__ __align__(16) char lds[49920];
  const int bid = blockIdx.x;
  const int t = threadIdx.x;
  if (bid < 768) {
    // ---------------- MLP ----------------
    int combo = bid >> 6;            // 0..11
    int bc = bid & 63;               // 32-row batch chunk
    int g = combo & 3;
    int dc = combo >> 2;             // 0: x[:,0:256], 1: hp[:,0:256], 2: hp[:,256:512]
    int d0g = dc * 256;
    int d = d0g + t;

    // stage+pack this combo's weight slice into LDS, fully coalesced:
    // linear float4 chunk f = t + i*256 -> row r = f>>3, quad kc4 = f&7
    f16x2* lw1 = (f16x2*)lds;                      // [16][260] f16x2
    f16x2* lb1 = (f16x2*)(lds + 16640);
    f16x2* lw2 = (f16x2*)(lds + 33280);
    {
      const float* S1 = W1 + ((size_t)g * D_ + d0g) * K_;
      const float* S2 = b1 + ((size_t)g * D_ + d0g) * K_;
      const float* S3 = W2 + ((size_t)g * D_ + d0g) * K_;
#pragma unroll
      for (int i = 0; i < 8; ++i) {
        int f = t + i * 256;
        int r = f >> 3, kc4 = f & 7;
        f32x4 v1 = *(const f32x4*)(S1 + (size_t)r * K_ + kc4 * 4);
        f32x4 v2 = *(const f32x4*)(S2 + (size_t)r * K_ + kc4 * 4);
        f32x4 v3 = *(const f32x4*)(S3 + (size_t)r * K_ + kc4 * 4);
        lw1[(kc4 * 2 + 0) * 260 + r] = pack2f(v1[0], v1[1]);
        lw1[(kc4 * 2 + 1) * 260 + r] = pack2f(v1[2], v1[3]);
        lb1[(kc4 * 2 + 0) * 260 + r] = pack2f(v2[0], v2[1]);
        lb1[(kc4 * 2 + 1) * 260 + r] = pack2f(v2[2], v2[3]);
        lw2[(kc4 * 2 + 0) * 260 + r] = pack2f(v3[0], v3[1]);
        lw2[(kc4 * 2 + 1) * 260 + r] = pack2f(v3[2], v3[3]);
      }
    }
    __syncthreads();
    f16x2 w1c[16], b1c[16], w2c[16];
#pragma unroll
    for (int kp = 0; kp < 16; ++kp) {            // own column, conflict-free
      w1c[kp] = lw1[kp * 260 + t];
      b1c[kp] = lb1[kp * 260 + t];
      w2c[kp] = lw2[kp * 260 + t];
    }
    float bias = b2[(size_t)g * D_ + d];

    const float* src = (dc == 0) ? (x + t) : (hp + ((dc == 1) ? t : t + 256));
    int stride = (dc == 0) ? I_ : H_;
    int b0 = bc * 32;
    ushort_t* up = uT + (size_t)g * B_ * D_ + (size_t)b0 * D_ + d;

    // hand-pipelined 4-chunk sequence: loads issue >=256 insts before use
    float cvA[8], cvB[8];
#define LOADC(ARR, JC)                                                       \
  _Pragma("unroll") for (int j = 0; j < 8; ++j)                              \
      ARR[j] = src[(size_t)(b0 + (JC) * 8 + j) * stride];
#define COMPC(ARR, JC)                                                       \
  {                                                                          \
    f16x2 cv2[8];                                                            \
    float acc[8];                                                            \
    _Pragma("unroll") for (int j = 0; j < 8; ++j) {                          \
      cv2[j] = pack2f(ARR[j], ARR[j]);                                       \
      acc[j] = 0.f;                                                          \
    }                                                                        \
    _Pragma("unroll") for (int kp = 0; kp < 16; ++kp)                        \
        _Pragma("unroll") for (int j = 0; j < 8; ++j) {                      \
      f16x2 h2 = pk_fma_relu(cv2[j], w1c[kp], b1c[kp]);                      \
      acc[j] = dot2_f32(h2, w2c[kp], acc[j]);                                \
    }                                                                        \
    _Pragma("unroll") for (int j = 0; j < 8; ++j)                            \
        up[(size_t)((JC) * 8 + j) * D_] = f2bf(bias + acc[j]);               \
  }
    LOADC(cvA, 0)
    LOADC(cvB, 1)
    COMPC(cvA, 0)
    LOADC(cvA, 2)
    COMPC(cvB, 1)
    LOADC(cvB, 3)
    COMPC(cvA, 2)
    COMPC(cvB, 3)
#undef LOADC
#undef COMPC
  } else {
    // ---------------- Wc transpose (64x64 tiles) ----------------
    int u = bid - 768;               // 0..383 = 4g x 12 d0 x 8 h0
    int g = u / 96;
    int rem = u % 96;
    int d0 = (rem >> 3) * 64;
    int h0 = (rem & 7) * 64;
    float* tt = (float*)lds;         // [64][65] f32
    int tx = t & 63, ty = t >> 6;
#pragma unroll
    for (int i = 0; i < 16; ++i) {
      int r = ty + i * 4;
      tt[r * 65 + tx] = Wc[((size_t)g * D_ + d0 + r) * H_ + h0 + tx];
    }
    __syncthreads();
#pragma unroll
    for (int i = 0; i < 16; ++i) {
      int hr = ty + i * 4;           // h index; lanes tx = consecutive d
      wcT[((size_t)g * H_ + h0 + hr) * D_ + d0 + tx] = f2bf(tt[tx * 65 + hr]);
    }
  }
}

// ---- phase 2 v7 (UNCHANGED anchor): 64(b) x 64(h) x 4 gates, 16 waves,
//      256 blocks (traffic-optimal tiling), NBUF=4 counted-vmcnt
//      global_load_lds pipeline, fused LSTM epilogue ----
#define TBM 64
#define THN 64
#define BK2 32
#define NT2 (D_ / BK2)               // 24
#define AREG 16384                   // A region bytes per buffer
#define BUF2 32768                   // per-buffer total (A 16K + B 16K)
#define NBUF2 4

__global__ __launch_bounds__(1024, 4) void kan_phase2(
    const ushort_t* __restrict__ uT, const ushort_t* __restrict__ wcT,
    const float* __restrict__ bc, const float* __restrict__ cprev,
    float* __restrict__ out) {
  __shared__ __align__(16) char smem[NBUF2 * BUF2];   // 131072 B
  const int b0 = blockIdx.x * TBM;
  const int h0 = blockIdx.y * THN;
  const int t = threadIdx.x;
  const int w = t >> 6;
  const int l = t & 63;
  const int g = w >> 2, mh = w & 3;    // wave = (gate, b-quarter)
  const int frow = l & 15, c0 = l >> 4;

  const int srow = t >> 2, sc = t & 3;
  const int sg = srow >> 6, sr = srow & 63;
  const int scg = sc ^ ((sr ^ (sr >> 2)) & 3);
  const ushort_t* asrc = uT + ((size_t)sg * B_ + b0 + sr) * D_ + scg * 8;
  const ushort_t* bsrc = wcT + ((size_t)sg * H_ + h0 + sr) * D_ + scg * 8;
  const int aLds = t * 16;
  const int bLds = AREG + t * 16;

  const int key = (frow ^ (frow >> 2)) & 3;
  const int cx = ((c0 ^ key) << 4);
  const int aoff = ((g * 64 + mh * 16 + frow) << 6) + cx;
  int boff[4];
#pragma unroll
  for (int n = 0; n < 4; ++n)
    boff[n] = AREG + ((g * 64 + n * 16 + frow) << 6) + cx;

  f32x4 acc[4];
#pragma unroll
  for (int n = 0; n < 4; ++n) {
    float bv = bc[(size_t)g * H_ + h0 + n * 16 + frow];
    acc[n] = (f32x4){bv, bv, bv, bv};
  }

  auto stage = [&](int bufoff, int ke) {
    gload16(asrc + ke, smem + bufoff + aLds);
    gload16(bsrc + ke, smem + bufoff + bLds);
  };
  auto compute = [&](const char* bb) {
    bf16x8 af = *(const bf16x8*)(bb + aoff);
    bf16x8 bf[4];
#pragma unroll
    for (int n = 0; n < 4; ++n) bf[n] = *(const bf16x8*)(bb + boff[n]);
    __builtin_amdgcn_s_setprio(1);
#pragma unroll
    for (int n = 0; n < 4; ++n)
      acc[n] = __builtin_amdgcn_mfma_f32_16x16x32_bf16(af, bf[n], acc[n], 0, 0, 0);
    __builtin_amdgcn_s_setprio(0);
  };

  stage(0 * BUF2, 0 * BK2);
  stage(1 * BUF2, 1 * BK2);
  stage(2 * BUF2, 2 * BK2);
  int s = 0;
  for (; s < NT2 - 3; ++s) {
    asm volatile("s_waitcnt vmcnt(4)" ::: "memory");
    __builtin_amdgcn_s_barrier();
    stage(((s + 3) & 3) * BUF2, (s + 3) * BK2);
    compute(smem + (s & 3) * BUF2);
  }
  asm volatile("s_waitcnt vmcnt(4)" ::: "memory");   // s = NT2-3
  __builtin_amdgcn_s_barrier();
  compute(smem + (s & 3) * BUF2);
  ++s;
  asm volatile("s_waitcnt vmcnt(2)" ::: "memory");   // s = NT2-2
  __builtin_amdgcn_s_barrier();
  compute(smem + (s & 3) * BUF2);
  ++s;
  asm volatile("s_waitcnt vmcnt(0)" ::: "memory");   // s = NT2-1
  __builtin_amdgcn_s_barrier();
  compute(smem + (s & 3) * BUF2);
  __syncthreads();

  float* gf = (float*)smem;
#pragma unroll
  for (int n = 0; n < 4; ++n)
#pragma unroll
    for (int e = 0; e < 4; ++e) {
      int row = mh * 16 + c0 * 4 + e;
      int col = n * 16 + frow;
      gf[((size_t)g * 64 + row) * 68 + col] = acc[n][e];
    }
  __syncthreads();

  {
    int row = t >> 4;                  // 0..63
    int ch = t & 15;
    int b = b0 + row;
    int hc = h0 + ch * 4;
    f32x4 g0 = *(const f32x4*)&gf[((size_t)0 * 64 + row) * 68 + ch * 4];
    f32x4 g1 = *(const f32x4*)&gf[((size_t)1 * 64 + row) * 68 + ch * 4];
    f32x4 g2 = *(const f32x4*)&gf[((size_t)2 * 64 + row) * 68 + ch * 4];
    f32x4 g3 = *(const f32x4*)&gf[((size_t)3 * 64 + row) * 68 + ch * 4];
    f32x4 cp = *(const f32x4*)&cprev[(size_t)b * H_ + hc];
    f32x4 hv, cv;
#pragma unroll
    for (int e = 0; e < 4; ++e) {
      float ft = fast_sigmoid(g0[e]);
      float it = fast_sigmoid(g1[e]);
      float ot = fast_sigmoid(g2[e]);
      float tc = fast_tanh(g3[e]);
      float cn = ft * cp[e] + it * tc;
      cv[e] = cn;
      hv[e] = ot * fast_tanh(cn);
    }
    *(f32x4*)&out[(size_t)b * H_ + hc] = hv;
    *(f32x4*)&out[(size_t)B_ * H_ + (size_t)b * H_ + hc] = cv;
  }
}

extern "C" void kernel_launch(void* const* d_in, const int* in_sizes, int n_in,
                              void* d_out, int out_size, void* d_ws, size_t ws_size,
                              hipStream_t stream) {
  const float* x  = (const float*)d_in[0];
  const float* hp = (const float*)d_in[1];
  const float* cp = (const float*)d_in[2];
  const float* W1 = (const float*)d_in[3];
  const float* b1 = (const float*)d_in[4];
  const float* W2 = (const float*)d_in[5];
  const float* b2 = (const float*)d_in[6];
  const float* Wc = (const float*)d_in[7];
  const float* bc = (const float*)d_in[8];
  float* out = (float*)d_out;

  // workspace layout
  ushort_t* wcT = (ushort_t*)d_ws;                  // 4*512*768 bf16
  ushort_t* uT  = wcT + (size_t)4 * H_ * D_;        // 4*2048*768 bf16

  kan_prep<<<1152, 256, 0, stream>>>(x, hp, W1, b1, W2, b2, Wc, wcT, uT);
  kan_phase2<<<dim3(B_ / TBM, H_ / THN), 1024, 0, stream>>>(uT, wcT, bc, cp, out);
}